// Round 6
// baseline (322.442 us; speedup 1.0000x reference)
//
#include <hip/hip_runtime.h>

// Inputs: floats fp32, ints int32. Outputs fp32 (verified round 7).
// Round 22: attntail 2-half split + aggemm packed accumulate.
//   - k_attntail: 256 threads; PV j-loop and msgW GEMV k-loop split across
//     two 128-thread halves (LDS recombine); LN tail uses duplicate-sum/2.
//     Serial chains halved, occupancy doubled.
//   - k_aggemm: gather accumulate in float2 ext-vectors via packed bf16-pair
//     unpack -> compiler can emit v_pk_add_f32 (2 adds/instr).
//   - cpl/cursor3/place unchanged.

typedef unsigned short ushort_t;
typedef unsigned int uint_t;
typedef __attribute__((ext_vector_type(8))) short bf16x8;   // 8 bf16 (MFMA A/B frag)
typedef __attribute__((ext_vector_type(4))) float floatx4;  // MFMA C/D frag
typedef __attribute__((ext_vector_type(2))) float f32x2;

// ---------- helpers ----------
__device__ __forceinline__ float b2f(ushort_t u) {
    union { unsigned int i; float f; } v; v.i = ((unsigned int)u) << 16; return v.f;
}
__device__ __forceinline__ f32x2 b2f2(uint_t u) {   // two packed bf16 -> two f32
    union { unsigned int i; float f; } lo, hi;
    lo.i = u << 16; hi.i = u & 0xFFFF0000u;
    f32x2 r; r.x = lo.f; r.y = hi.f; return r;
}
__device__ __forceinline__ ushort_t f2b(float f) {
    union { float f; unsigned int i; } v; v.f = f;
    unsigned int x = v.i;
    return (ushort_t)((x + 0x7FFFu + ((x >> 16) & 1u)) >> 16);   // RTNE
}
__device__ __forceinline__ float gelu_f(float x) {
    return 0.5f * x * (1.0f + erff(x * 0.70710678118654752440f)); // exact gelu
}
__device__ __forceinline__ float waveReduceSum(float v) {
#pragma unroll
    for (int o = 32; o; o >>= 1) v += __shfl_xor(v, o, 64);
    return v;
}
__device__ __forceinline__ int waveReduceSumI(int v) {
#pragma unroll
    for (int o = 32; o; o >>= 1) v += __shfl_xor(v, o, 64);
    return v;
}
__device__ __forceinline__ float waveReduceMax(float v) {
#pragma unroll
    for (int o = 32; o; o >>= 1) v = fmaxf(v, __shfl_xor(v, o, 64));
    return v;
}
__device__ __forceinline__ int lowerBound(const int* __restrict__ a, int n, int v) {
    int lo = 0, hi = n;
    while (lo < hi) { int mid = (lo + hi) >> 1; if (a[mid] < v) lo = mid + 1; else hi = mid; }
    return lo;
}

// ---------- 1. fused: edge count (0..ebc) | Wt prep (+128) | LN1 (rest) ----------
__global__ void __launch_bounds__(256) k_cpl(
    const float* __restrict__ x, const float* __restrict__ w, const float* __restrict__ b,
    const float* __restrict__ Wl, const float* __restrict__ Wr,
    const int* __restrict__ ei, int* __restrict__ deg,
    ushort_t* __restrict__ Wt, ushort_t* __restrict__ hb, int N, int E, int ebc) {
    int bid = blockIdx.x;
    if (bid < ebc) {             // ---- count role: 8 edges/thread, int4 x2
        int i0 = (bid * 256 + threadIdx.x) * 8;
        const int* dstp = ei + E;
        if (i0 + 7 < E) {
            int4 a = *(const int4*)(dstp + i0);
            int4 c = *(const int4*)(dstp + i0 + 4);
            atomicAdd(&deg[a.x], 1); atomicAdd(&deg[a.y], 1);
            atomicAdd(&deg[a.z], 1); atomicAdd(&deg[a.w], 1);
            atomicAdd(&deg[c.x], 1); atomicAdd(&deg[c.y], 1);
            atomicAdd(&deg[c.z], 1); atomicAdd(&deg[c.w], 1);
        } else {
            int e1 = min(i0 + 8, E);
            for (int i = i0; i < e1; i++) atomicAdd(&deg[dstp[i]], 1);
        }
        return;
    }
    bid -= ebc;
    if (bid < 128) {             // ---- prep role: Wt[n][k] = bf16 concat-T of Wl;Wr
        int id = bid * 256 + threadIdx.x;        // exactly 32768 threads
        int n = id >> 8, k = id & 255;
        float v = (k < 128) ? Wl[k * 128 + n] : Wr[(k - 128) * 128 + n];
        Wt[n * 256 + k] = f2b(v);
        return;
    }
    int lb = bid - 128;          // ---- ln1 role: 4 rows per block, 1 wave per row
    int row  = lb * 4 + (threadIdx.x >> 6);
    int lane = threadIdx.x & 63;
    if (row >= N) return;
    size_t base = (size_t)row * 128;
    float2 xv = ((const float2*)(x + base))[lane];
    float v0 = xv.x, v1 = xv.y;
    float s  = waveReduceSum(v0 + v1);
    float s2 = waveReduceSum(v0 * v0 + v1 * v1);
    float mu = s * (1.0f / 128.0f);
    float var = s2 * (1.0f / 128.0f) - mu * mu;
    float rstd = 1.0f / sqrtf(var + 1e-5f);
    int d = lane * 2;
    ushort2 ov;
    ov.x = f2b((v0 - mu) * rstd * w[d]     + b[d]);
    ov.y = f2b((v1 - mu) * rstd * w[d + 1] + b[d + 1]);
    ((ushort2*)(hb + base))[lane] = ov;
}

// ---------- 2. cursor: redundant prefix reduce + Kogge-Stone scan -> cursor,wcur ----
__global__ void __launch_bounds__(256) k_cursor3(
    const int* __restrict__ deg, int* __restrict__ cursor, int* __restrict__ wcur, int N) {
    int c = blockIdx.x, t = threadIdx.x;
    __shared__ int sb[256];
    __shared__ int cw[4];
    int lim = c << 8;
    int part = 0;
    for (int j = t; j < lim; j += 256) part += deg[j];
    part = waveReduceSumI(part);
    int lane = t & 63, wv = t >> 6;
    if (lane == 0) cw[wv] = part;
    int i = (c << 8) + t;
    int v = (i < N) ? deg[i] : 0;
    sb[t] = v;
    __syncthreads();
    for (int o = 1; o < 256; o <<= 1) {
        int a = (t >= o) ? sb[t - o] : 0;
        __syncthreads();
        sb[t] += a;
        __syncthreads();
    }
    int coff = cw[0] + cw[1] + cw[2] + cw[3];
    if (i < N) {
        int cv = sb[t] - v + coff;     // exclusive scan = row start
        cursor[i] = cv;
        wcur[i]   = cv;
    }
}

// ---------- 3. direct placement: 8 edges/thread, atomics batched before stores ------
__global__ void __launch_bounds__(256) k_place(
    const int* __restrict__ ei, int* __restrict__ wcur, int* __restrict__ nbr, int E) {
    int i0 = (blockIdx.x * 256 + threadIdx.x) * 8;
    if (i0 + 7 < E) {
        int4 s0 = *(const int4*)(ei + i0);
        int4 s1 = *(const int4*)(ei + i0 + 4);
        int4 d0 = *(const int4*)(ei + E + i0);
        int4 d1 = *(const int4*)(ei + E + i0 + 4);
        int p0 = atomicAdd(&wcur[d0.x], 1);
        int p1 = atomicAdd(&wcur[d0.y], 1);
        int p2 = atomicAdd(&wcur[d0.z], 1);
        int p3 = atomicAdd(&wcur[d0.w], 1);
        int p4 = atomicAdd(&wcur[d1.x], 1);
        int p5 = atomicAdd(&wcur[d1.y], 1);
        int p6 = atomicAdd(&wcur[d1.z], 1);
        int p7 = atomicAdd(&wcur[d1.w], 1);
        nbr[p0] = s0.x; nbr[p1] = s0.y; nbr[p2] = s0.z; nbr[p3] = s0.w;
        nbr[p4] = s1.x; nbr[p5] = s1.y; nbr[p6] = s1.z; nbr[p7] = s1.w;
    } else {
        int e1 = min(i0 + 8, E);
        for (int i = i0; i < e1; i++) {
            int s = ei[i], d = ei[E + i];
            nbr[atomicAdd(&wcur[d], 1)] = s;
        }
    }
}

// ---------- 4. fused: CSR mean-gather -> MFMA GEMM -> LN -> gelu -> gate ----------
__global__ void __launch_bounds__(256) k_aggemm(
    const ushort_t* __restrict__ hb, const ushort_t* __restrict__ Wt,
    const float* __restrict__ bl, const float* __restrict__ lnw,
    const float* __restrict__ lnb, const float* __restrict__ gw,
    const float* __restrict__ gb, const int* __restrict__ deg,
    const int* __restrict__ cursor, const int* __restrict__ nbr,
    ushort_t* __restrict__ h3b, float* __restrict__ gate, int N) {
    __shared__ ushort_t A[16][264];   // [m][k], pad 264
    __shared__ float H2[16][132];
    int t = threadIdx.x;
    int row0 = blockIdx.x * 16;
    int w = t >> 6, l = t & 63;
    int sub = l >> 4, li = l & 15;
    // ---- phase 0: each subgroup aggregates its own node (row r = w*4+sub) ----
    {
        int r = w * 4 + sub;
        int node = row0 + r; if (node >= N) node = N - 1;
        bf16x8 hv = *(const bf16x8*)(hb + (size_t)node * 128 + li * 8);
        *(bf16x8*)&A[r][128 + li * 8] = hv;
        int dg = deg[node];
        int st = cursor[node];
        f32x2 a0 = {0.f, 0.f}, a1 = {0.f, 0.f}, a2 = {0.f, 0.f}, a3 = {0.f, 0.f};
        const uint_t* hp = (const uint_t*)hb;
#define ROWPTR(s) ((const uint4*)(hp + (size_t)(s) * 64 + li * 4))
#define ACCQ(q) { a0 += b2f2((q).x); a1 += b2f2((q).y); a2 += b2f2((q).z); a3 += b2f2((q).w); }
        int j = 0;
        for (; j + 8 <= dg; j += 8) {        // 8 independent row loads in flight
            uint4 q0 = *ROWPTR(nbr[st + j]);
            uint4 q1 = *ROWPTR(nbr[st + j + 1]);
            uint4 q2 = *ROWPTR(nbr[st + j + 2]);
            uint4 q3 = *ROWPTR(nbr[st + j + 3]);
            uint4 q4 = *ROWPTR(nbr[st + j + 4]);
            uint4 q5 = *ROWPTR(nbr[st + j + 5]);
            uint4 q6 = *ROWPTR(nbr[st + j + 6]);
            uint4 q7 = *ROWPTR(nbr[st + j + 7]);
            ACCQ(q0); ACCQ(q1); ACCQ(q2); ACCQ(q3);
            ACCQ(q4); ACCQ(q5); ACCQ(q6); ACCQ(q7);
        }
        for (; j + 4 <= dg; j += 4) {
            uint4 q0 = *ROWPTR(nbr[st + j]);
            uint4 q1 = *ROWPTR(nbr[st + j + 1]);
            uint4 q2 = *ROWPTR(nbr[st + j + 2]);
            uint4 q3 = *ROWPTR(nbr[st + j + 3]);
            ACCQ(q0); ACCQ(q1); ACCQ(q2); ACCQ(q3);
        }
        for (; j < dg; j++) {
            uint4 q0 = *ROWPTR(nbr[st + j]);
            ACCQ(q0);
        }
#undef ROWPTR
#undef ACCQ
        float inv = 1.0f / fmaxf((float)dg, 1.0f);
        bf16x8 ov;
        ov[0] = (short)f2b(a0.x * inv); ov[1] = (short)f2b(a0.y * inv);
        ov[2] = (short)f2b(a1.x * inv); ov[3] = (short)f2b(a1.y * inv);
        ov[4] = (short)f2b(a2.x * inv); ov[5] = (short)f2b(a2.y * inv);
        ov[6] = (short)f2b(a3.x * inv); ov[7] = (short)f2b(a3.y * inv);
        *(bf16x8*)&A[r][li * 8] = ov;
    }
    __syncthreads();
    // ---- phase 1: MFMA over K=256 ----
    int m16 = l & 15, quad = l >> 4;
    int n0 = w * 32 + m16;
    int n1 = n0 + 16;
    floatx4 acc0 = {0.f, 0.f, 0.f, 0.f}, acc1 = {0.f, 0.f, 0.f, 0.f};
    for (int ks = 0; ks < 256; ks += 32) {
        bf16x8 a  = *(const bf16x8*)&A[m16][ks + quad * 8];
        bf16x8 b0 = *(const bf16x8*)(Wt + (size_t)n0 * 256 + ks + quad * 8);
        bf16x8 b1 = *(const bf16x8*)(Wt + (size_t)n1 * 256 + ks + quad * 8);
        acc0 = __builtin_amdgcn_mfma_f32_16x16x32_bf16(a, b0, acc0, 0, 0, 0);
        acc1 = __builtin_amdgcn_mfma_f32_16x16x32_bf16(a, b1, acc1, 0, 0, 0);
    }
#pragma unroll
    for (int i = 0; i < 4; i++) {
        H2[quad * 4 + i][n0] = acc0[i];
        H2[quad * 4 + i][n1] = acc1[i];
    }
    __syncthreads();
    // ---- phase 2: +bias, LN, gelu, gate; h3 -> h3b ----
    int d = l * 2;
    float bb0 = bl[d],  bb1 = bl[d + 1];
    float lw0 = lnw[d], lw1 = lnw[d + 1];
    float lb0 = lnb[d], lb1 = lnb[d + 1];
    float gw0 = gw[d],  gw1 = gw[d + 1];
    float gbias = gb[0];
#pragma unroll
    for (int rr = 0; rr < 4; rr++) {
        int r = w * 4 + rr;
        int row = row0 + r;
        if (row >= N) break;
        float v0 = H2[r][d] + bb0, v1 = H2[r][d + 1] + bb1;
        float s  = waveReduceSum(v0 + v1);
        float s2 = waveReduceSum(v0 * v0 + v1 * v1);
        float mu = s * (1.f / 128.f);
        float var = s2 * (1.f / 128.f) - mu * mu;
        float rstd = 1.0f / sqrtf(var + 1e-5f);
        float g0 = gelu_f((v0 - mu) * rstd * lw0 + lb0);
        float g1 = gelu_f((v1 - mu) * rstd * lw1 + lb1);
        float gp = waveReduceSum(g0 * gw0 + g1 * gw1);
        ushort2 ov; ov.x = f2b(g0); ov.y = f2b(g1);
        ((ushort2*)(h3b + (size_t)row * 128))[l] = ov;
        if (l == 0) gate[row] = gp + gbias;
    }
}

// ---------- 5. fused attn+head, 256 threads: two halves split PV & GEMV ----------
__global__ void __launch_bounds__(256) k_attntail(
    const float* __restrict__ gate, const ushort_t* __restrict__ h3b,
    const int* __restrict__ batch,
    const float* __restrict__ text, const float* __restrict__ feats,
    const float* __restrict__ msgW, const float* __restrict__ msgb,
    const float* __restrict__ featW, const float* __restrict__ featb,
    const float* __restrict__ gwt, const float* __restrict__ mixw,
    const float* __restrict__ mixb, const float* __restrict__ fc1W,
    const float* __restrict__ fc1b,
    float* __restrict__ ge_out, float* __restrict__ attn_out,
    float* __restrict__ logits, int N, int G) {
    int g = blockIdx.x, tid = threadIdx.x;
    int h = tid >> 7, t = tid & 127;
    __shared__ int sbound[2];
    __shared__ float wbuf[4];
    __shared__ float pbuf[256];
    __shared__ float txt[768];
    __shared__ float accb[256];
    __shared__ float rbuf[8];
    if (tid < 2) sbound[tid] = lowerBound(batch, N, g + tid);
    for (int i = tid; i < 768; i += 256) txt[i] = text[(size_t)g * 768 + i];
    __syncthreads();
    int s0 = sbound[0], s1 = sbound[1];
    int lane = tid & 63, wv = tid >> 6;
    float acc = 0.f;
    if (s1 > s0) {                       // block-uniform branch
        float m = -3.0e38f;
        for (int i = s0 + tid; i < s1; i += 256) m = fmaxf(m, gate[i]);
        m = waveReduceMax(m);
        if (lane == 0) wbuf[wv] = m;
        __syncthreads();
        m = fmaxf(fmaxf(wbuf[0], wbuf[1]), fmaxf(wbuf[2], wbuf[3]));
        __syncthreads();
        float dsum = 0.f;
        for (int i = s0 + tid; i < s1; i += 256) dsum += expf(gate[i] - m);
        dsum = waveReduceSum(dsum);
        if (lane == 0) wbuf[wv] = dsum;
        __syncthreads();
        float inv = 1.0f / (wbuf[0] + wbuf[1] + wbuf[2] + wbuf[3]);
        for (int base = s0; base < s1; base += 256) {
            int n = min(256, s1 - base);
            __syncthreads();
            if (tid < n) {
                float p = expf(gate[base + tid] - m) * inv;
                pbuf[tid] = p;
                attn_out[base + tid] = p;
            }
            __syncthreads();
            int j1 = min(n, h * 128 + 128);          // half h covers [h*128, j1)
            for (int j = h * 128; j < j1; j++)
                acc += pbuf[j] * b2f(h3b[(size_t)(base + j) * 128 + t]);
        }
    }
    accb[tid] = acc;
    __syncthreads();
    acc = accb[t] + accb[t + 128];                   // both halves get full acc
    if (h == 0) ge_out[(size_t)g * 128 + t] = acc;
    // ---- head: msgW GEMV split over halves (k in [h*384, h*384+384)) ----
    float am = (h == 0) ? msgb[t] : 0.f;
    int k0 = h * 384;
    for (int k = k0; k < k0 + 384; k += 4) {
        float4 a = *(const float4*)&txt[k];
        am += a.x * msgW[(k + 0) * 128 + t] + a.y * msgW[(k + 1) * 128 + t]
            + a.z * msgW[(k + 2) * 128 + t] + a.w * msgW[(k + 3) * 128 + t];
    }
    __syncthreads();                                  // accb reuse
    accb[tid] = am;
    __syncthreads();
    am = accb[t] + accb[t + 128];
    float me = gelu_f(am);
    float af = featb[t];
#pragma unroll
    for (int k = 0; k < 14; k++) af += feats[g * 14 + k] * featW[k * 128 + t];
    float fe = gelu_f(af);
    float e0 = gwt[0] * acc;
    // ---- mixed LN over 384 dims: both halves duplicate -> sum/2 ----
    float ps = e0 + me + fe, ps2 = e0 * e0 + me * me + fe * fe;
    float r1 = waveReduceSum(ps), r2 = waveReduceSum(ps2);
    __syncthreads();
    if (lane == 0) { rbuf[wv] = r1; rbuf[4 + wv] = r2; }
    __syncthreads();
    float S  = (rbuf[0] + rbuf[1] + rbuf[2] + rbuf[3]) * 0.5f;
    float S2 = (rbuf[4] + rbuf[5] + rbuf[6] + rbuf[7]) * 0.5f;
    float mu = S * (1.f / 384.f);
    float var = S2 * (1.f / 384.f) - mu * mu;
    float rstd = 1.0f / sqrtf(var + 1e-5f);
    float n0 = (e0 - mu) * rstd * mixw[t]       + mixb[t];
    float n1 = (me - mu) * rstd * mixw[128 + t] + mixb[128 + t];
    float n2 = (fe - mu) * rstd * mixw[256 + t] + mixb[256 + t];
    float lp = n0 * fc1W[t] + n1 * fc1W[128 + t] + n2 * fc1W[256 + t];
    float r3 = waveReduceSum(lp);
    __syncthreads();
    if (lane == 0) rbuf[wv] = r3;
    __syncthreads();
    if (tid == 0)
        logits[g] = (rbuf[0] + rbuf[1] + rbuf[2] + rbuf[3]) * 0.5f + fc1b[0];
}

// ---------- launch ----------
extern "C" void kernel_launch(void* const* d_in, const int* in_sizes, int n_in,
                              void* d_out, int out_size, void* d_ws, size_t ws_size,
                              hipStream_t stream) {
    const float* x     = (const float*)d_in[0];
    const int*   ei    = (const int*)d_in[1];
    const int*   batch = (const int*)d_in[2];
    const float* text  = (const float*)d_in[4];
    const float* feats = (const float*)d_in[5];
    const float* lnpw  = (const float*)d_in[6];
    const float* lnpb  = (const float*)d_in[7];
    const float* Wl    = (const float*)d_in[8];
    const float* bl    = (const float*)d_in[9];
    const float* Wr    = (const float*)d_in[10];
    const float* lncw  = (const float*)d_in[11];
    const float* lncb  = (const float*)d_in[12];
    const float* gatew = (const float*)d_in[13];
    const float* gateb = (const float*)d_in[14];
    const float* gwt   = (const float*)d_in[15];
    const float* msgW  = (const float*)d_in[16];
    const float* msgb  = (const float*)d_in[17];
    const float* featW = (const float*)d_in[18];
    const float* featb = (const float*)d_in[19];
    const float* mixw  = (const float*)d_in[20];
    const float* mixb  = (const float*)d_in[21];
    const float* fc1W  = (const float*)d_in[22];
    const float* fc1b  = (const float*)d_in[23];

    int N = in_sizes[0] / 128;
    int E = in_sizes[1] / 2;
    int G = in_sizes[4] / 768;

    char* wp = (char*)d_ws;
    auto alloc = [&](size_t bytes) -> char* {
        char* p = wp; wp += (bytes + 255) & ~(size_t)255; return p;
    };
    ushort_t* hb     = (ushort_t*)alloc((size_t)N * 128 * 2);   // h (bf16), read-only after cpl
    ushort_t* h3b    = (ushort_t*)alloc((size_t)N * 128 * 2);   // h3 (bf16) from aggemm
    ushort_t* Wt     = (ushort_t*)alloc(128 * 256 * 2);
    float*    gate   = (float*)alloc((size_t)N * 4);
    int*      deg    = (int*)alloc((size_t)N * 4);
    int*      cursor = (int*)alloc((size_t)N * 4);
    int*      wcur   = (int*)alloc((size_t)N * 4);
    int*      nbr    = (int*)alloc((size_t)E * 4);

    int nch = (N + 255) / 256;    // 196 chunks of 256 nodes
    int ebc = (E + 2047) / 2048;  // 8 edges/thread, 256 threads (391)

    // OUTPUTS fp32, flat in return order:
    float* logits_out = (float*)d_out;                 // [G, 1]
    float* ge_out     = logits_out + G;                // [G, 128]
    float* attn_out   = ge_out + (size_t)G * 128;      // [N, 1]

    hipMemsetAsync(deg, 0, (size_t)N * 4, stream);
    k_cpl      <<<ebc + 128 + (N + 3) / 4, 256, 0, stream>>>(
                                                   x, lnpw, lnpb, Wl, Wr, ei, deg,
                                                   Wt, hb, N, E, ebc);
    k_cursor3  <<<nch,               256, 0, stream>>>(deg, cursor, wcur, N);
    k_place    <<<ebc,               256, 0, stream>>>(ei, wcur, nbr, E);
    k_aggemm   <<<(N + 15) / 16,     256, 0, stream>>>(hb, Wt, bl, lncw, lncb, gatew, gateb,
                                                       deg, cursor, nbr, h3b, gate, N);
    k_attntail <<<G,                 256, 0, stream>>>(gate, h3b, batch, text, feats,
                                                       msgW, msgb, featW, featb, gwt,
                                                       mixw, mixb, fc1W, fc1b,
                                                       ge_out, attn_out, logits_out, N, G);
}